// Round 13
// baseline (222.112 us; speedup 1.0000x reference)
//
#include <hip/hip_runtime.h>

typedef float f32x2 __attribute__((ext_vector_type(2)));
typedef unsigned int u32;

#define NIT 21
#define SMIN 1e-33f

// DPP quad-perm / row-rotate all-reduce over each 16-lane group (VALU pipe).
template<int CTRL>
static __device__ __forceinline__ float dppmov(float v) {
    return __int_as_float(__builtin_amdgcn_mov_dpp(__float_as_int(v), CTRL, 0xF, 0xF, true));
}
static __device__ __forceinline__ float sum16(float v) {
    v += dppmov<0xB1>(v);    // xor1
    v += dppmov<0x4E>(v);    // xor2
    v += dppmov<0x124>(v);   // row_ror:4
    v += dppmov<0x128>(v);   // row_ror:8
    return v;
}
static __device__ __forceinline__ float max16(float v) {
    v = fmaxf(v, dppmov<0xB1>(v));
    v = fmaxf(v, dppmov<0x4E>(v));
    v = fmaxf(v, dppmov<0x124>(v));
    v = fmaxf(v, dppmov<0x128>(v));
    return v;
}

#if __has_builtin(__builtin_amdgcn_permlane16_swap) && __has_builtin(__builtin_amdgcn_permlane32_swap)
#define HAVE_PLSWAP 1
// validated on HW in round 10
static __device__ __forceinline__ float plsum16(float A, float B) {
    auto r = __builtin_amdgcn_permlane16_swap(__float_as_uint(A), __float_as_uint(B), false, false);
    return __uint_as_float(r[0]) + __uint_as_float(r[1]);
}
static __device__ __forceinline__ float plsum32(float X, float Y) {
    auto r = __builtin_amdgcn_permlane32_swap(__float_as_uint(X), __float_as_uint(Y), false, false);
    return __uint_as_float(r[0]) + __uint_as_float(r[1]);
}
#else
#define HAVE_PLSWAP 0
#endif

// One 256-thread block per 128x128 matrix (8x8 tile/thread). Linear-space
// Sinkhorn: E = 2^((x-m)*S) fixed in registers; lazy rcp factors a_i/b_j.
// Round-13: r12 was latency-bound (VALU-busy-time fell 152->134us, wall flat)
// with unified VGPR+AGPR alloc ~128/wave -> 4 waves/EU cap. waves_per_eu(5,5)
// caps ~102 regs; readback restructured to f32x2 pairwise adds to halve its
// peak liveness (was 8 float4 = 32 floats in flight). FETCH_SIZE is the spill
// tripwire (131MB good / r11's cap-85 ballooned to 237MB).
__global__ void __attribute__((amdgpu_flat_work_group_size(256, 256),
                               amdgpu_waves_per_eu(5, 5)))
sinkhorn_kernel(const float* __restrict__ in, float* __restrict__ out) {
    const int t  = threadIdx.x;
    const int rg = t >> 4;      // row-group 0..15 (rows rg*8..+7)
    const int cg = t & 15;      // col-group (cols cg*8..+7); == lane&15
    const int wv = t >> 6;      // wave 0..3
    const int q  = rg & 3;      // 16-lane row index within wave
    const u32 off = ((u32)blockIdx.x << 14) + ((u32)rg << 10) + ((u32)cg << 3);
    const float* __restrict__ src = in  + off;
    float*       __restrict__ dst = out + off;

    const float S = 36.067376022224085f;  // (1/0.04) * log2(e)

    f32x2 E[8][4];
    float a[8];
    f32x2 b2[4];

    // ---- init: row max, E = 2^((x-m)*S), a = rcp(rowsum) ----
#pragma unroll
    for (int i = 0; i < 8; ++i) {
        float4 f0 = *(const float4*)(src + (i << 7));
        float4 f1 = *(const float4*)(src + (i << 7) + 4);
        E[i][0] = (f32x2){f0.x, f0.y};
        E[i][1] = (f32x2){f0.z, f0.w};
        E[i][2] = (f32x2){f1.x, f1.y};
        E[i][3] = (f32x2){f1.z, f1.w};
        f32x2 m2 = E[i][0];
#pragma unroll
        for (int j = 1; j < 4; ++j) {
            m2.x = fmaxf(m2.x, E[i][j].x);
            m2.y = fmaxf(m2.y, E[i][j].y);
        }
        float m = max16(fmaxf(m2.x, m2.y));
        const float nms = -m * S;
        float s = 0.f;
#pragma unroll
        for (int j = 0; j < 4; ++j) {
            f32x2 e;
            e.x = __builtin_amdgcn_exp2f(fmaf(E[i][j].x, S, nms));
            e.y = __builtin_amdgcn_exp2f(fmaf(E[i][j].y, S, nms));
            E[i][j] = e;
            s += e.x + e.y;
        }
        s = sum16(s);
        a[i] = __builtin_amdgcn_rcpf(fmaxf(s, SMIN));   // rowsum in [1,128]
    }

    // col partials: [dbuf][wave][128 floats]; float idx cg*4+q (cols 0..3 of
    // group cg) and 64+cg*4+q (cols 4..7) -> f32x2 readback at pair idx.
    __shared__ float part[2][4][128];
    int pb = 0;

#pragma unroll 1
    for (int it = 0; it < NIT; ++it) {
        // ---- col phase: b_j = rcp( sum_i E_ij * a_i ) ----
        f32x2 sc[4];
#pragma unroll
        for (int j = 0; j < 4; ++j) sc[j] = (f32x2){0.f, 0.f};
#pragma unroll
        for (int i = 0; i < 8; ++i) {
            const f32x2 ai2 = {a[i], a[i]};
#pragma unroll
            for (int j = 0; j < 4; ++j) sc[j] += E[i][j] * ai2;
        }
#if HAVE_PLSWAP
        // in-wave reduce over the 4 row-groups, all VALU (validated r10)
        float s01 = plsum16(sc[0].x, sc[0].y);
        float s23 = plsum16(sc[1].x, sc[1].y);
        float s45 = plsum16(sc[2].x, sc[2].y);
        float s67 = plsum16(sc[3].x, sc[3].y);
        float X1 = plsum32(s01, s23);
        float X2 = plsum32(s45, s67);
        part[pb][wv][(cg << 2) + q]      = X1;
        part[pb][wv][64 + (cg << 2) + q] = X2;
#else
#pragma unroll
        for (int j = 0; j < 4; ++j) {
            sc[j].x += __shfl_xor(sc[j].x, 16); sc[j].y += __shfl_xor(sc[j].y, 16);
            sc[j].x += __shfl_xor(sc[j].x, 32); sc[j].y += __shfl_xor(sc[j].y, 32);
        }
        if ((t & 63) < 16) {
            float4* p4 = (float4*)part[pb][wv];
            p4[cg]      = make_float4(sc[0].x, sc[0].y, sc[1].x, sc[1].y);
            p4[16 + cg] = make_float4(sc[2].x, sc[2].y, sc[3].x, sc[3].y);
        }
#endif
        __syncthreads();
        {
            // pairwise f32x2 tree: halves peak liveness vs 8 concurrent float4
            const f32x2* p0 = (const f32x2*)part[pb][0];
            const f32x2* p1 = (const f32x2*)part[pb][1];
            const f32x2* p2 = (const f32x2*)part[pb][2];
            const f32x2* p3 = (const f32x2*)part[pb][3];
            const int e0 = cg << 1;        // pair idx for cols 0..3 (2 f32x2)
            const int e1 = (cg << 1) + 32; // pair idx for cols 4..7
#pragma unroll
            for (int h = 0; h < 2; ++h) {
                const int e = h ? e1 : e0;
                f32x2 u0 = p0[e]     + p1[e];
                f32x2 v0 = p2[e]     + p3[e];
                f32x2 u1 = p0[e + 1] + p1[e + 1];
                f32x2 v1 = p2[e + 1] + p3[e + 1];
                u0 += v0;
                u1 += v1;
                b2[2 * h].x     = __builtin_amdgcn_rcpf(fmaxf(u0.x, SMIN));
                b2[2 * h].y     = __builtin_amdgcn_rcpf(fmaxf(u0.y, SMIN));
                b2[2 * h + 1].x = __builtin_amdgcn_rcpf(fmaxf(u1.x, SMIN));
                b2[2 * h + 1].y = __builtin_amdgcn_rcpf(fmaxf(u1.y, SMIN));
            }
        }
        pb ^= 1;

        // ---- row phase: a_i = rcp( sum_j E_ij * b_j )  (skip after last col) ----
        if (it < NIT - 1) {
#pragma unroll
            for (int i = 0; i < 8; ++i) {
                f32x2 s2 = E[i][0] * b2[0];
                s2 += E[i][1] * b2[1];
                s2 += E[i][2] * b2[2];
                s2 += E[i][3] * b2[3];
                float s = sum16(s2.x + s2.y);
                a[i] = __builtin_amdgcn_rcpf(fmaxf(s, SMIN));
            }
        }
    }

    // ---- epilogue: out = E * a_i * b_j ----
#pragma unroll
    for (int i = 0; i < 8; ++i) {
        const float ai = a[i];
        f32x2 p0 = E[i][0] * b2[0];
        f32x2 p1 = E[i][1] * b2[1];
        f32x2 p2 = E[i][2] * b2[2];
        f32x2 p3 = E[i][3] * b2[3];
        float4 o0 = make_float4(p0.x * ai, p0.y * ai, p1.x * ai, p1.y * ai);
        float4 o1 = make_float4(p2.x * ai, p2.y * ai, p3.x * ai, p3.y * ai);
        *(float4*)(dst + (i << 7))     = o0;
        *(float4*)(dst + (i << 7) + 4) = o1;
    }
}

extern "C" void kernel_launch(void* const* d_in, const int* in_sizes, int n_in,
                              void* d_out, int out_size, void* d_ws, size_t ws_size,
                              hipStream_t stream) {
    (void)n_in; (void)d_ws; (void)ws_size; (void)out_size;
    const float* in  = (const float*)d_in[0];
    float*       out = (float*)d_out;
    const int n_mat = in_sizes[0] / (128 * 128);  // 4096
    sinkhorn_kernel<<<dim3(n_mat), dim3(256), 0, stream>>>(in, out);
}

// Round 14
// 175.345 us; speedup vs baseline: 1.2667x; 1.2667x over previous
//
#include <hip/hip_runtime.h>

typedef short bf16x8 __attribute__((ext_vector_type(8)));
typedef float f32x4 __attribute__((ext_vector_type(4)));
typedef unsigned int u32;
typedef unsigned short u16;

#define NIT 21
#define SMIN 1e-33f
#define LDSCOL 136   // padded row stride in u16: 272B = 16B-aligned, banks spread (68 dw % 32 = 4)

static __device__ __forceinline__ u16 f2bf(float f) {   // RNE pack (validated r8)
    u32 u = __float_as_uint(f);
    u = (u + 0x7fffu + ((u >> 16) & 1u)) >> 16;
    return (u16)u;
}
static __device__ __forceinline__ float bf2f(u16 h) {
    return __uint_as_float(((u32)h) << 16);
}

// MFMA Sinkhorn: one 256-thread block per 128x128 matrix. E = bf16(2^((x-m)*S))
// held as per-wave MFMA fragments: af = row-tiles (A-operand, rows w*32+th*16),
// bf = col-tiles (B-operand, cols w*32+uh*16). Each phase is a matvec done as
// 8 chained v_mfma_f32_16x16x32_bf16 (K reduced inside the MFMA - no DPP/shfl
// trees). a/b vectors live in 256B LDS; a lane's 8 k-values = 1 ds_read_b128
// which IS the replicated vector fragment. Layout-permutation-robust: both
// operands of each mfma use the same assumed (lane,slot)->k map, so any HW
// k-permutation cancels in the dot product. C/D layout per m89 (HW-verified):
// row=(lane>>4)*4+reg, col=lane&15.
__global__ void __attribute__((amdgpu_flat_work_group_size(256, 256)))
sinkhorn_kernel(const float* __restrict__ in, float* __restrict__ out) {
    const int t  = threadIdx.x;
    const int w  = t >> 6;         // wave 0..3
    const int lg = (t >> 4) & 3;   // k-group within wave
    const int ln = t & 15;         // m (row-tiles) / n (col-tiles) within tile
    const size_t mat = (size_t)blockIdx.x << 14;
    const float S = 36.067376022224085f;   // (1/0.04)*log2(e)

    __shared__ __align__(16) u16 E_lds[128 * LDSCOL];
    __shared__ __align__(16) u16 a_lds[128];
    __shared__ __align__(16) u16 b_lds[128];

    bf16x8 af[2][4];   // row-tile fragments: af[th][c] = E[w*32+th*16+ln][c*32+lg*8 ..+7]

    // ---- init: load, rowmax, E = bf16(2^((x-m)*S)), stage row-major to LDS, a = rcp(rowsum) ----
#pragma unroll
    for (int th = 0; th < 2; ++th) {
        const int M = w * 32 + th * 16 + ln;
        const float* src = in + mat + (size_t)M * 128 + lg * 8;
        float v[4][8];
        float m = -3.4e38f;
#pragma unroll
        for (int c = 0; c < 4; ++c) {
            float4 f0 = *(const float4*)(src + c * 32);
            float4 f1 = *(const float4*)(src + c * 32 + 4);
            v[c][0] = f0.x; v[c][1] = f0.y; v[c][2] = f0.z; v[c][3] = f0.w;
            v[c][4] = f1.x; v[c][5] = f1.y; v[c][6] = f1.z; v[c][7] = f1.w;
#pragma unroll
            for (int j = 0; j < 8; ++j) m = fmaxf(m, v[c][j]);
        }
        // row M is held by the 4 lanes {ln, ln+16, ln+32, ln+48}
        m = fmaxf(m, __shfl_xor(m, 16));
        m = fmaxf(m, __shfl_xor(m, 32));
        const float nms = -m * S;
        float s = 0.f;
#pragma unroll
        for (int c = 0; c < 4; ++c) {
            bf16x8 fr;
#pragma unroll
            for (int j = 0; j < 8; ++j) {
                float e = __builtin_amdgcn_exp2f(fmaf(v[c][j], S, nms));
                s += e;
                fr[j] = (short)f2bf(e);
            }
            af[th][c] = fr;
            *(bf16x8*)&E_lds[M * LDSCOL + c * 32 + lg * 8] = fr;   // 16B-aligned
        }
        s += __shfl_xor(s, 16);
        s += __shfl_xor(s, 32);
        if (lg == 0) {
            a_lds[M] = f2bf(__builtin_amdgcn_rcpf(fmaxf(s, SMIN)));  // rowsum in [1,128]
        }
    }
    __syncthreads();

    // ---- col-tile fragments (B-operand): bf[uh][c] = E[c*32+lg*8+j][w*32+uh*16+ln] ----
    bf16x8 bf[2][4];
#pragma unroll
    for (int uh = 0; uh < 2; ++uh) {
        const int N = w * 32 + uh * 16 + ln;
#pragma unroll
        for (int c = 0; c < 4; ++c) {
            bf16x8 fr;
#pragma unroll
            for (int j = 0; j < 8; ++j)
                fr[j] = (short)E_lds[(c * 32 + lg * 8 + j) * LDSCOL + N];
            bf[uh][c] = fr;
        }
    }

    const f32x4 z4 = {0.f, 0.f, 0.f, 0.f};

#pragma unroll 1
    for (int it = 0; it < NIT; ++it) {
        // ---- col phase: colsum_n = sum_k a_k E_kn  (A = a replicated over m) ----
        f32x4 acc0 = z4, acc1 = z4;
#pragma unroll
        for (int c = 0; c < 4; ++c) {
            bf16x8 aop = *(const bf16x8*)&a_lds[c * 32 + lg * 8];
            acc0 = __builtin_amdgcn_mfma_f32_16x16x32_bf16(aop, bf[0][c], acc0, 0, 0, 0);
            acc1 = __builtin_amdgcn_mfma_f32_16x16x32_bf16(aop, bf[1][c], acc1, 0, 0, 0);
        }
        // D rows all identical; lane holds col n=ln of its tile; lg==0 lanes write
        if (lg == 0) {
            b_lds[w * 32 + ln]      = f2bf(__builtin_amdgcn_rcpf(fmaxf(acc0[0], SMIN)));
            b_lds[w * 32 + 16 + ln] = f2bf(__builtin_amdgcn_rcpf(fmaxf(acc1[0], SMIN)));
        }
        __syncthreads();

        // ---- row phase: rowsum_m = sum_k E_mk b_k  (B = b replicated over n) ----
        if (it < NIT - 1) {
            f32x4 r0 = z4, r1 = z4;
#pragma unroll
            for (int c = 0; c < 4; ++c) {
                bf16x8 bop = *(const bf16x8*)&b_lds[c * 32 + lg * 8];
                r0 = __builtin_amdgcn_mfma_f32_16x16x32_bf16(af[0][c], bop, r0, 0, 0, 0);
                r1 = __builtin_amdgcn_mfma_f32_16x16x32_bf16(af[1][c], bop, r1, 0, 0, 0);
            }
            // D cols all identical; lane holds rows lg*4+reg of its tile; ln==0 lanes write
            if (ln == 0) {
#pragma unroll
                for (int r = 0; r < 4; ++r) {
                    a_lds[w * 32 +      lg * 4 + r] = f2bf(__builtin_amdgcn_rcpf(fmaxf(r0[r], SMIN)));
                    a_lds[w * 32 + 16 + lg * 4 + r] = f2bf(__builtin_amdgcn_rcpf(fmaxf(r1[r], SMIN)));
                }
            }
            __syncthreads();
        }
    }

    // ---- epilogue: out = E * a_m * b_n ----
#pragma unroll
    for (int th = 0; th < 2; ++th) {
        const int M = w * 32 + th * 16 + ln;
        float* dst = out + mat + (size_t)M * 128 + lg * 8;
        const float av = bf2f(a_lds[M]);
#pragma unroll
        for (int c = 0; c < 4; ++c) {
            const bf16x8 e = af[th][c];
            const bf16x8 bop = *(const bf16x8*)&b_lds[c * 32 + lg * 8];
            float4 o0, o1;
            o0.x = bf2f((u16)e[0]) * av * bf2f((u16)bop[0]);
            o0.y = bf2f((u16)e[1]) * av * bf2f((u16)bop[1]);
            o0.z = bf2f((u16)e[2]) * av * bf2f((u16)bop[2]);
            o0.w = bf2f((u16)e[3]) * av * bf2f((u16)bop[3]);
            o1.x = bf2f((u16)e[4]) * av * bf2f((u16)bop[4]);
            o1.y = bf2f((u16)e[5]) * av * bf2f((u16)bop[5]);
            o1.z = bf2f((u16)e[6]) * av * bf2f((u16)bop[6]);
            o1.w = bf2f((u16)e[7]) * av * bf2f((u16)bop[7]);
            *(float4*)(dst + c * 32)     = o0;
            *(float4*)(dst + c * 32 + 4) = o1;
        }
    }
}

extern "C" void kernel_launch(void* const* d_in, const int* in_sizes, int n_in,
                              void* d_out, int out_size, void* d_ws, size_t ws_size,
                              hipStream_t stream) {
    (void)n_in; (void)d_ws; (void)ws_size; (void)out_size;
    const float* in  = (const float*)d_in[0];
    float*       out = (float*)d_out;
    const int n_mat = in_sizes[0] / (128 * 128);  // 4096
    sinkhorn_kernel<<<dim3(n_mat), dim3(256), 0, stream>>>(in, out);
}